// Round 9
// baseline (151.755 us; speedup 1.0000x reference)
//
#include <hip/hip_runtime.h>

#define HH 260
#define WW 346
#define CC 1212            // real channel count (pred layout)
#define CP 1280            // padded compact space: [0,640) pol0, [640,1280) pol1
#define HALF 640
#define NA 606             // active channels per polarity (260 + 346)
#define BB 16
#define TT 4096
#define INV_TEMP (1.0f/256.0f)
#define KCH 256            // chunks per batch
#define LCH 16             // TT / KCH
#define NG 16              // groups per batch
#define GSZ 16             // chunks per group
#define GLEN (GSZ * LCH)   // 256
#define NJ 10              // compact registers per polarity set (640/64)

// ------ Fused phase 1+2a (+2b tail): one channel per thread, suffix scan over a group ------
// grid: (b*NG+g)*5 + sl, 256 threads; thread owns channel c = sl*256+tid.
// Per step: wave-uniform d (exp of LDS-broadcast timestamps), 1 fma + 2 cmp-add.
// Last block per batch b performs the 16-group super-scan (deterministic order).
__global__ __launch_bounds__(256) void p12_scan(const float* __restrict__ target,
                                                float* __restrict__ LCin,
                                                float* __restrict__ GroupL,
                                                float* __restrict__ SC,
                                                int* __restrict__ ctr) {
    const int blk = blockIdx.x;
    const int sl = blk % 5;
    const int bg = blk / 5;
    const int b = bg >> 4, g = bg & 15;
    const int tid = threadIdx.x;
    const int c = sl * 256 + tid;          // [0,1280)
    const int a0 = g * GLEN;

    __shared__ float tg[GLEN][4];
    __shared__ float tnextS;
    __shared__ int lastS;
    for (int idx = tid; idx < GLEN * 4; idx += 256)
        tg[idx >> 2][idx & 3] = target[((size_t)b * TT + a0) * 4 + idx];
    if (tid == 0) tnextS = (a0 + GLEN < TT) ? target[((size_t)b * TT + a0 + GLEN) * 4] : 0.0f;
    __syncthreads();

    float carry = 0.f;
    for (int k = GSZ - 1; k >= 0; --k) {
        LCin[((size_t)(b * KCH + g * GSZ + k)) * CP + c] = carry;
#pragma unroll
        for (int q = LCH - 1; q >= 0; --q) {
            const int li = k * LCH + q;
            const int i = a0 + li;
            const float ti = tg[li][0];
            const float tn = (li == GLEN - 1) ? tnextS : tg[li + 1][0];
            const float d = (i >= TT - 1) ? 0.f : __expf(-(tn - ti) * INV_TEMP);
            const int y = (int)tg[li][1], x = (int)tg[li][2], p = (int)tg[li][3];
            const int cy = p * HALF + y;
            const int cx = p * HALF + 260 + x;
            const float add = ((c == cy) ? 1.f : 0.f) + ((c == cx) ? 1.f : 0.f);
            carry = fmaf(carry, d, add);
        }
    }
    GroupL[(size_t)bg * CP + c] = carry;

    // -------- fused p2b: last block of this batch does the group super-scan --------
    __syncthreads();                       // drains this block's global stores (vmcnt 0)
    if (tid == 0) {
        __threadfence();                   // flush L2 so GroupL is globally visible
        lastS = (atomicAdd(&ctr[b], 1) == NG * 5 - 1) ? 1 : 0;
    }
    __syncthreads();
    if (lastS) {
        __threadfence();                   // acquire: invalidate stale caches
        for (int it = 0; it < 5; ++it) {
            const int cc = it * 256 + tid;
            float Gv[NG];
#pragma unroll
            for (int gg = 0; gg < NG; ++gg)
                Gv[gg] = GroupL[((size_t)(b * NG + gg)) * CP + cc];
            float c2 = 0.f;
#pragma unroll
            for (int gg = NG - 1; gg >= 0; --gg) {
                SC[((size_t)(b * NG + gg)) * CP + cc] = c2;
                float GP = 0.f;
                if (gg < NG - 1) {
                    const float ta = target[((size_t)b * TT + gg * GLEN) * 4];
                    const float te = target[((size_t)b * TT + (gg + 1) * GLEN) * 4];
                    GP = __expf(-(te - ta) * INV_TEMP);
                }
                c2 = fmaf(GP, c2, Gv[gg]);
            }
        }
    }
}

// ------- Phase 3: replay + fused loss, 4 chunks/block; fused final reduction -------
__global__ __launch_bounds__(256, 4) void p3_loss(const float* __restrict__ pred,
                                                  const float* __restrict__ target,
                                                  const float* __restrict__ LCin,
                                                  const float* __restrict__ SC,
                                                  double* __restrict__ partials,
                                                  float* __restrict__ out,
                                                  int* __restrict__ ctr) {
    const int blk = blockIdx.x;            // BB*KCH/4
    const int b = blk >> 6;
    const int k0 = (blk & 63) << 2;
    const int tid = threadIdx.x;
    const int w = tid >> 6, lane = tid & 63;
    const int k = k0 + w;
    const int g = k >> 4;
    const int a = k * LCH;

    __shared__ float tg[4][LCH][4];
    __shared__ float tnextS[4];
    __shared__ int lastS;
    __shared__ double sred[4];
    tg[tid >> 6][(tid >> 2) & 15][tid & 3] =
        target[((size_t)b * TT + k0 * LCH) * 4 + tid];
    if (tid < 4) {
        const int kk = k0 + tid;
        tnextS[tid] = (kk < KCH - 1) ? target[((size_t)b * TT + (kk + 1) * LCH) * 4] : 0.0f;
    }
    __syncthreads();

    // carry(k) = LCin[k] + Qk * SC[group], Qk = exp(-(t[groupEnd] - t[a_{k+1}])/T)
    float Qk = 0.f;
    if (g < NG - 1) {
        const float tge = target[((size_t)b * TT + (g + 1) * GLEN) * 4];
        const float tk1 = target[((size_t)b * TT + (k + 1) * LCH) * 4];
        Qk = __expf(-(tge - tk1) * INV_TEMP);
    }

    const float* __restrict__ lc = LCin + (size_t)(b * KCH + k) * CP;
    const float* __restrict__ sc = SC + ((size_t)(b * NG + g)) * CP;
    float s0[NJ], s1[NJ];
#pragma unroll
    for (int j = 0; j < NJ; ++j) {
        const int u = lane + 64 * j;
        s0[j] = fmaf(Qk, sc[u], lc[u]);
        s1[j] = fmaf(Qk, sc[HALF + u], lc[HALF + u]);
    }

    float prA[NJ], prB[NJ];
    {
        const int p = (int)tg[w][LCH - 1][3];
        const float* __restrict__ prow = pred + ((size_t)b * TT + a + LCH - 1) * CC;
#pragma unroll
        for (int j = 0; j < NJ; ++j) {
            const int u = lane + 64 * j;
            const int c = (u < 260) ? p * HH + u : 2 * HH + p * WW + (u - 260);
            prA[j] = (u < NA) ? prow[c] : 0.0f;
        }
    }

    double lacc = 0.0;
    for (int li = LCH - 1; li >= 0; --li) {
        if (li > 0) {
            const int pn = (int)tg[w][li - 1][3];
            const float* __restrict__ prow = pred + ((size_t)b * TT + a + li - 1) * CC;
#pragma unroll
            for (int j = 0; j < NJ; ++j) {
                const int u = lane + 64 * j;
                const int c = (u < 260) ? pn * HH + u : 2 * HH + pn * WW + (u - 260);
                prB[j] = (u < NA) ? prow[c] : 0.0f;
            }
        }

        const int i = a + li;
        const float ti = tg[w][li][0];
        const float tn = (li == LCH - 1) ? tnextS[w] : tg[w][li + 1][0];
        const float d = (i == 0 || i >= TT - 1) ? 0.0f : __expf(-(tn - ti) * INV_TEMP);
        const int y = (int)tg[w][li][1], x = (int)tg[w][li][2], p = (int)tg[w][li][3];
        const int uy = y, ux = 260 + x;

        float zpy = 0.f, zsy = 0.f, dty = 0.f;
        float zpx = 0.f, zsx = 0.f, dtx = 0.f;

        auto inner = [&](float (&SA)[NJ], float (&SO)[NJ]) {
#pragma unroll
            for (int j = 0; j < NJ; ++j) {
                const int u = lane + 64 * j;
                const float add = (u == uy ? 1.f : 0.f) + (u == ux ? 1.f : 0.f);
                SA[j] = fmaf(SA[j], d, add);
                SO[j] *= d;
                float es = __expf(SA[j]);
                float ep = __expf(prA[j]);
                if (j == NJ - 1) {               // mask pad lanes (u >= 606)
                    const float m = (u < NA) ? 1.f : 0.f;
                    es *= m; ep *= m;
                }
                if (j < 4) {                     // u <= 255: pure y
                    zpy += ep; zsy += es; dty = fmaf(es, prA[j], dty);
                } else if (j == 4) {             // u in [256,320): mixed at 260
                    const bool isY = (u < 260);
                    zpy += isY ? ep : 0.f;
                    zsy += isY ? es : 0.f;
                    dty = fmaf(isY ? es : 0.f, prA[j], dty);
                    zpx += isY ? 0.f : ep;
                    zsx += isY ? 0.f : es;
                    dtx = fmaf(isY ? 0.f : es, prA[j], dtx);
                } else {                         // pure x
                    zpx += ep; zsx += es; dtx = fmaf(es, prA[j], dtx);
                }
            }
        };
        if (p == 0) inner(s0, s1); else inner(s1, s0);

#pragma unroll
        for (int off = 32; off > 0; off >>= 1) {
            zpy += __shfl_xor(zpy, off);
            zsy += __shfl_xor(zsy, off);
            dty += __shfl_xor(dty, off);
            zpx += __shfl_xor(zpx, off);
            zsx += __shfl_xor(zsx, off);
            dtx += __shfl_xor(dtx, off);
        }
        const float loss = __logf(zpy) + __logf(zpx)
                         - __fdividef(dty, zsy) - __fdividef(dtx, zsx);
        lacc += (double)loss;

#pragma unroll
        for (int j = 0; j < NJ; ++j) prA[j] = prB[j];
    }
    if (lane == 0) partials[b * KCH + k] = lacc;

    // -------- fused finalize: last block reduces all partials (fixed order) --------
    __syncthreads();                       // drains partials stores
    if (tid == 0) {
        __threadfence();
        lastS = (atomicAdd(&ctr[16], 1) == (int)gridDim.x - 1) ? 1 : 0;
    }
    __syncthreads();
    if (lastS) {                           // block-uniform
        __threadfence();
        double sum = 0.0;
        for (int i2 = tid; i2 < BB * KCH; i2 += 256) sum += partials[i2];
#pragma unroll
        for (int off = 32; off > 0; off >>= 1) sum += __shfl_xor(sum, off);
        if ((tid & 63) == 0) sred[tid >> 6] = sum;
        __syncthreads();
        if (tid == 0)
            out[0] = (float)((sred[0] + sred[1] + sred[2] + sred[3]) / (double)((size_t)BB * TT));
    }
}

extern "C" void kernel_launch(void* const* d_in, const int* in_sizes, int n_in,
                              void* d_out, int out_size, void* d_ws, size_t ws_size,
                              hipStream_t stream) {
    const float* pred   = (const float*)d_in[0];
    const float* target = (const float*)d_in[1];
    float* out = (float*)d_out;

    // ws layout: [partials 4096 doubles = 32KB][ctr 32 ints][pad to 64KB][LCin][GroupL][SC]
    double* partials = (double*)d_ws;
    int* ctr = (int*)((char*)d_ws + 32768);
    float* LCin   = (float*)((char*)d_ws + 65536);
    float* GroupL = LCin + (size_t)BB * KCH * CP;
    float* SC     = GroupL + (size_t)BB * NG * CP;

    hipMemsetAsync(ctr, 0, 32 * sizeof(int), stream);
    p12_scan<<<BB * NG * 5, 256, 0, stream>>>(target, LCin, GroupL, SC, ctr);
    p3_loss<<<BB * KCH / 4, 256, 0, stream>>>(pred, target, LCin, SC, partials, out, ctr);
}

// Round 10
// 83.224 us; speedup vs baseline: 1.8235x; 1.8235x over previous
//
#include <hip/hip_runtime.h>

#define HH 260
#define WW 346
#define CC 1212            // real channel count (pred layout)
#define CP 1280            // padded compact space: [0,640) pol0, [640,1280) pol1
#define HALF 640
#define NA 606             // active channels per polarity (260 + 346)
#define BB 16
#define TT 4096
#define INV_TEMP (1.0f/256.0f)
#define KCH 256            // chunks per batch
#define LCH 16             // TT / KCH
#define NG 16              // groups per batch
#define GSZ 16             // chunks per group
#define GLEN (GSZ * LCH)   // 256
#define NJ 10              // compact registers per polarity set (640/64)

// ---------------- Phase 1: per-chunk local state (zero carry), 4 chunks/block ----------------
__global__ __launch_bounds__(256) void p1_local(const float* __restrict__ target,
                                                float* __restrict__ Lbuf) {
    const int blk = blockIdx.x;            // BB*KCH/4
    const int b = blk >> 6;
    const int k0 = (blk & 63) << 2;
    const int tid = threadIdx.x;
    const int w = tid >> 6, lane = tid & 63;
    const int k = k0 + w;
    const int a = k * LCH;

    __shared__ float tg[4][LCH][4];
    __shared__ float tnextS[4];
    tg[tid >> 6][(tid >> 2) & 15][tid & 3] =
        target[((size_t)b * TT + k0 * LCH) * 4 + tid];
    if (tid < 4) {
        const int kk = k0 + tid;
        tnextS[tid] = (kk < KCH - 1) ? target[((size_t)b * TT + (kk + 1) * LCH) * 4] : 0.0f;
    }
    __syncthreads();

    float s0[NJ], s1[NJ];
#pragma unroll
    for (int j = 0; j < NJ; ++j) { s0[j] = 0.f; s1[j] = 0.f; }

    for (int li = LCH - 1; li >= 0; --li) {
        const int i = a + li;
        const float ti = tg[w][li][0];
        const float tn = (li == LCH - 1) ? tnextS[w] : tg[w][li + 1][0];
        const float d = (i >= TT - 1) ? 0.0f : __expf(-(tn - ti) * INV_TEMP);
        const int y = (int)tg[w][li][1], x = (int)tg[w][li][2], p = (int)tg[w][li][3];
        const int uy = y, ux = 260 + x;
        if (p == 0) {
#pragma unroll
            for (int j = 0; j < NJ; ++j) {
                const int u = lane + 64 * j;
                const float add = (u == uy ? 1.f : 0.f) + (u == ux ? 1.f : 0.f);
                s0[j] = fmaf(s0[j], d, add);
                s1[j] *= d;
            }
        } else {
#pragma unroll
            for (int j = 0; j < NJ; ++j) {
                const int u = lane + 64 * j;
                const float add = (u == uy ? 1.f : 0.f) + (u == ux ? 1.f : 0.f);
                s1[j] = fmaf(s1[j], d, add);
                s0[j] *= d;
            }
        }
    }
    float* __restrict__ out = Lbuf + (size_t)(b * KCH + k) * CP;
#pragma unroll
    for (int j = 0; j < NJ; ++j) {
        out[lane + 64 * j] = s0[j];
        out[HALF + lane + 64 * j] = s1[j];
    }
}

// ------- Phase 2a: within-group (16 chunks) suffix combine -------
__global__ __launch_bounds__(256) void p2a(const float* __restrict__ target,
                                           const float* __restrict__ Lbuf,
                                           float* __restrict__ LCin,
                                           float* __restrict__ GroupL) {
    const int blk = blockIdx.x;            // BB*NG*5
    const int ct = blk % 5;
    const int bg = blk / 5;                // b*NG + g
    const int b = bg >> 4, g = bg & 15;
    const int c = ct * 256 + threadIdx.x;  // < CP

    float carry = 0.f;
#pragma unroll
    for (int kk = GSZ - 1; kk >= 0; --kk) {
        const int k = g * GSZ + kk;
        const size_t idx = ((size_t)(b * KCH + k)) * CP + c;
        LCin[idx] = carry;
        float P = 0.f;
        if (k < KCH - 1) {
            const float ta = target[((size_t)b * TT + k * LCH) * 4];
            const float te = target[((size_t)b * TT + (k + 1) * LCH) * 4];
            P = __expf(-(te - ta) * INV_TEMP);
        }
        carry = fmaf(P, carry, Lbuf[idx]);
    }
    GroupL[(size_t)bg * CP + c] = carry;
}

// ------- Phase 2b: super-scan across 16 groups (preloaded) -------
__global__ __launch_bounds__(256) void p2b(const float* __restrict__ target,
                                           const float* __restrict__ GroupL,
                                           float* __restrict__ SC) {
    const int blk = blockIdx.x;            // BB*5
    const int ct = blk % 5;
    const int b = blk / 5;
    const int c = ct * 256 + threadIdx.x;

    float Gv[NG], GP[NG];
#pragma unroll
    for (int g = 0; g < NG; ++g)
        Gv[g] = GroupL[((size_t)(b * NG + g)) * CP + c];
#pragma unroll
    for (int g = 0; g < NG; ++g) {
        if (g < NG - 1) {
            const float ta = target[((size_t)b * TT + g * GLEN) * 4];
            const float te = target[((size_t)b * TT + (g + 1) * GLEN) * 4];
            GP[g] = __expf(-(te - ta) * INV_TEMP);
        } else GP[g] = 0.f;
    }
    float carry = 0.f;
#pragma unroll
    for (int g = NG - 1; g >= 0; --g) {
        SC[((size_t)(b * NG + g)) * CP + c] = carry;
        carry = fmaf(GP[g], carry, Gv[g]);
    }
}

// ------- Phase 3: replay + fused loss, POLARITY-PLANE SPLIT (2 waves per chunk) -------
// wave (b,k,q) owns plane q (640 ch, 10 regs). Steps with p==q do the full loss;
// other steps just decay. 8192 waves, <=64 VGPR -> 8 waves/SIMD.
__global__ __launch_bounds__(256, 8) void p3_loss(const float* __restrict__ pred,
                                                  const float* __restrict__ target,
                                                  const float* __restrict__ LCin,
                                                  const float* __restrict__ SC,
                                                  double* __restrict__ partials) {
    const int blk = blockIdx.x;            // BB*KCH/4
    const int q = blockIdx.y;              // plane/polarity this wave serves
    const int b = blk >> 6;
    const int k0 = (blk & 63) << 2;
    const int tid = threadIdx.x;
    const int w = tid >> 6, lane = tid & 63;
    const int k = k0 + w;
    const int g = k >> 4;
    const int a = k * LCH;

    __shared__ float tg[4][LCH][4];
    __shared__ float tnextS[4];
    tg[tid >> 6][(tid >> 2) & 15][tid & 3] =
        target[((size_t)b * TT + k0 * LCH) * 4 + tid];
    if (tid < 4) {
        const int kk = k0 + tid;
        tnextS[tid] = (kk < KCH - 1) ? target[((size_t)b * TT + (kk + 1) * LCH) * 4] : 0.0f;
    }
    __syncthreads();

    // carry(k) = LCin[k] + Qk * SC[group] (plane-q slice only)
    float Qk = 0.f;
    if (g < NG - 1) {
        const float tge = target[((size_t)b * TT + (g + 1) * GLEN) * 4];
        const float tk1 = target[((size_t)b * TT + (k + 1) * LCH) * 4];
        Qk = __expf(-(tge - tk1) * INV_TEMP);
    }

    const float* __restrict__ lc = LCin + (size_t)(b * KCH + k) * CP + q * HALF;
    const float* __restrict__ sc = SC + ((size_t)(b * NG + g)) * CP + q * HALF;
    float s[NJ];
#pragma unroll
    for (int j = 0; j < NJ; ++j) {
        const int u = lane + 64 * j;
        s[j] = fmaf(Qk, sc[u], lc[u]);
    }

    double lacc = 0.0;
    for (int li = LCH - 1; li >= 0; --li) {
        const int i = a + li;
        const float ti = tg[w][li][0];
        const float tn = (li == LCH - 1) ? tnextS[w] : tg[w][li + 1][0];
        const float d = (i == 0 || i >= TT - 1) ? 0.0f : __expf(-(tn - ti) * INV_TEMP);
        const int y = (int)tg[w][li][1], x = (int)tg[w][li][2], p = (int)tg[w][li][3];

        if (p != q) {                       // inactive step: pure decay (wave-uniform)
#pragma unroll
            for (int j = 0; j < NJ; ++j) s[j] *= d;
            continue;
        }

        const int uy = y, ux = 260 + x;
        const float* __restrict__ prow = pred + ((size_t)b * TT + i) * CC;

        float zpy = 0.f, zsy = 0.f, dty = 0.f;
        float zpx = 0.f, zsx = 0.f, dtx = 0.f;
#pragma unroll
        for (int j = 0; j < NJ; ++j) {
            const int u = lane + 64 * j;
            const float add = (u == uy ? 1.f : 0.f) + (u == ux ? 1.f : 0.f);
            s[j] = fmaf(s[j], d, add);
            const int c = (u < 260) ? q * HH + u : 2 * HH + q * WW + (u - 260);
            const float pr = (u < NA) ? prow[c] : 0.0f;
            float es = __expf(s[j]);
            float ep = __expf(pr);
            if (j == NJ - 1) {               // mask pad lanes (u >= 606)
                const float m = (u < NA) ? 1.f : 0.f;
                es *= m; ep *= m;
            }
            if (j < 4) {                     // u <= 255: pure y
                zpy += ep; zsy += es; dty = fmaf(es, pr, dty);
            } else if (j == 4) {             // u in [256,320): mixed at 260
                const bool isY = (u < 260);
                zpy += isY ? ep : 0.f;
                zsy += isY ? es : 0.f;
                dty = fmaf(isY ? es : 0.f, pr, dty);
                zpx += isY ? 0.f : ep;
                zsx += isY ? 0.f : es;
                dtx = fmaf(isY ? 0.f : es, pr, dtx);
            } else {                         // pure x
                zpx += ep; zsx += es; dtx = fmaf(es, pr, dtx);
            }
        }

#pragma unroll
        for (int off = 32; off > 0; off >>= 1) {
            zpy += __shfl_xor(zpy, off);
            zsy += __shfl_xor(zsy, off);
            dty += __shfl_xor(dty, off);
            zpx += __shfl_xor(zpx, off);
            zsx += __shfl_xor(zsx, off);
            dtx += __shfl_xor(dtx, off);
        }
        const float loss = __logf(zpy) + __logf(zpx)
                         - __fdividef(dty, zsy) - __fdividef(dtx, zsx);
        lacc += (double)loss;
    }
    if (lane == 0) partials[q * (BB * KCH) + b * KCH + k] = lacc;
}

// ---------------- Finalize: sum 2*B*KCH partials ----------------
__global__ void p4_final(const double* __restrict__ partials, float* __restrict__ out) {
    const int tid = threadIdx.x;   // 256
    double sum = 0.0;
    for (int i = tid; i < 2 * BB * KCH; i += 256) sum += partials[i];
#pragma unroll
    for (int off = 32; off > 0; off >>= 1) sum += __shfl_xor(sum, off);
    __shared__ double sred[4];
    if ((tid & 63) == 0) sred[tid >> 6] = sum;
    __syncthreads();
    if (tid == 0)
        out[0] = (float)((sred[0] + sred[1] + sred[2] + sred[3]) / (double)((size_t)BB * TT));
}

extern "C" void kernel_launch(void* const* d_in, const int* in_sizes, int n_in,
                              void* d_out, int out_size, void* d_ws, size_t ws_size,
                              hipStream_t stream) {
    const float* pred   = (const float*)d_in[0];
    const float* target = (const float*)d_in[1];
    float* out = (float*)d_out;

    // ws layout: [partials 8192 doubles = 64KB][Lbuf][LCin][GroupL][SC]
    double* partials = (double*)d_ws;
    float* Lbuf   = (float*)((char*)d_ws + 65536);
    float* LCin   = Lbuf + (size_t)BB * KCH * CP;
    float* GroupL = LCin + (size_t)BB * KCH * CP;
    float* SC     = GroupL + (size_t)BB * NG * CP;

    p1_local<<<BB * KCH / 4, 256, 0, stream>>>(target, Lbuf);
    p2a<<<BB * NG * 5, 256, 0, stream>>>(target, Lbuf, LCin, GroupL);
    p2b<<<BB * 5, 256, 0, stream>>>(target, GroupL, SC);
    dim3 g3(BB * KCH / 4, 2);
    p3_loss<<<g3, 256, 0, stream>>>(pred, target, LCin, SC, partials);
    p4_final<<<1, 256, 0, stream>>>(partials, out);
}

// Round 12
// 83.189 us; speedup vs baseline: 1.8242x; 1.0004x over previous
//
#include <hip/hip_runtime.h>

#define HH 260
#define WW 346
#define CC 1212            // real channel count (pred layout)
#define CP 1280            // padded compact space: [0,640) pol0, [640,1280) pol1
#define HALF 640
#define NA 606             // active channels per polarity (260 + 346)
#define BB 16
#define TT 4096
#define INV_TEMP (1.0f/256.0f)
#define KCH 256            // chunks per batch
#define LCH 16             // TT / KCH
#define NG 16              // groups per batch
#define GSZ 16             // chunks per group
#define GLEN (GSZ * LCH)   // 256
#define NJ 10              // compact registers per polarity set (640/64)

// v += DPP-permuted(v); permutation stays within a 16-lane row -> VALU pipe, no LDS
template <int CTRL>
__device__ __forceinline__ float dpp_add(float v) {
    const int t = __builtin_amdgcn_update_dpp(0, __float_as_int(v), CTRL, 0xF, 0xF, true);
    return v + __int_as_float(t);
}
// full 64-lane sum, only 2 DS ops (xor16, xor32); xor1/xor2 via quad_perm,
// xor4/xor8 via row_ror (rotate-reduce is exact for sums within a 16-lane row)
__device__ __forceinline__ float wave_sum(float v) {
    v = dpp_add<0xB1>(v);    // quad_perm [1,0,3,2]  (xor1)
    v = dpp_add<0x4E>(v);    // quad_perm [2,3,0,1]  (xor2)
    v = dpp_add<0x124>(v);   // row_ror:4
    v = dpp_add<0x128>(v);   // row_ror:8
    v += __shfl_xor(v, 16);  // DS
    v += __shfl_xor(v, 32);  // DS
    return v;
}

// ---------------- Phase 1: per-chunk local state (zero carry), 4 chunks/block ----------------
__global__ __launch_bounds__(256) void p1_local(const float* __restrict__ target,
                                                float* __restrict__ Lbuf) {
    const int blk = blockIdx.x;            // BB*KCH/4
    const int b = blk >> 6;
    const int k0 = (blk & 63) << 2;
    const int tid = threadIdx.x;
    const int w = tid >> 6, lane = tid & 63;
    const int k = k0 + w;
    const int a = k * LCH;

    __shared__ float tg[4][LCH][4];
    __shared__ float tnextS[4];
    tg[tid >> 6][(tid >> 2) & 15][tid & 3] =
        target[((size_t)b * TT + k0 * LCH) * 4 + tid];
    if (tid < 4) {
        const int kk = k0 + tid;
        tnextS[tid] = (kk < KCH - 1) ? target[((size_t)b * TT + (kk + 1) * LCH) * 4] : 0.0f;
    }
    __syncthreads();

    float s0[NJ], s1[NJ];
#pragma unroll
    for (int j = 0; j < NJ; ++j) { s0[j] = 0.f; s1[j] = 0.f; }

    for (int li = LCH - 1; li >= 0; --li) {
        const int i = a + li;
        const float ti = tg[w][li][0];
        const float tn = (li == LCH - 1) ? tnextS[w] : tg[w][li + 1][0];
        const float d = (i >= TT - 1) ? 0.0f : __expf(-(tn - ti) * INV_TEMP);
        const int y = (int)tg[w][li][1], x = (int)tg[w][li][2], p = (int)tg[w][li][3];
        const int uy = y, ux = 260 + x;
        if (p == 0) {
#pragma unroll
            for (int j = 0; j < NJ; ++j) {
                const int u = lane + 64 * j;
                const float add = (u == uy ? 1.f : 0.f) + (u == ux ? 1.f : 0.f);
                s0[j] = fmaf(s0[j], d, add);
                s1[j] *= d;
            }
        } else {
#pragma unroll
            for (int j = 0; j < NJ; ++j) {
                const int u = lane + 64 * j;
                const float add = (u == uy ? 1.f : 0.f) + (u == ux ? 1.f : 0.f);
                s1[j] = fmaf(s1[j], d, add);
                s0[j] *= d;
            }
        }
    }
    float* __restrict__ out = Lbuf + (size_t)(b * KCH + k) * CP;
#pragma unroll
    for (int j = 0; j < NJ; ++j) {
        out[lane + 64 * j] = s0[j];
        out[HALF + lane + 64 * j] = s1[j];
    }
}

// ------- Phase 2a: within-group (16 chunks) suffix combine -------
__global__ __launch_bounds__(256) void p2a(const float* __restrict__ target,
                                           const float* __restrict__ Lbuf,
                                           float* __restrict__ LCin,
                                           float* __restrict__ GroupL) {
    const int blk = blockIdx.x;            // BB*NG*5
    const int ct = blk % 5;
    const int bg = blk / 5;                // b*NG + g
    const int b = bg >> 4, g = bg & 15;
    const int c = ct * 256 + threadIdx.x;  // < CP

    float carry = 0.f;
#pragma unroll
    for (int kk = GSZ - 1; kk >= 0; --kk) {
        const int k = g * GSZ + kk;
        const size_t idx = ((size_t)(b * KCH + k)) * CP + c;
        LCin[idx] = carry;
        float P = 0.f;
        if (k < KCH - 1) {
            const float ta = target[((size_t)b * TT + k * LCH) * 4];
            const float te = target[((size_t)b * TT + (k + 1) * LCH) * 4];
            P = __expf(-(te - ta) * INV_TEMP);
        }
        carry = fmaf(P, carry, Lbuf[idx]);
    }
    GroupL[(size_t)bg * CP + c] = carry;
}

// ------- Phase 2b: super-scan across 16 groups (preloaded) -------
__global__ __launch_bounds__(256) void p2b(const float* __restrict__ target,
                                           const float* __restrict__ GroupL,
                                           float* __restrict__ SC) {
    const int blk = blockIdx.x;            // BB*5
    const int ct = blk % 5;
    const int b = blk / 5;
    const int c = ct * 256 + threadIdx.x;

    float Gv[NG], GP[NG];
#pragma unroll
    for (int g = 0; g < NG; ++g)
        Gv[g] = GroupL[((size_t)(b * NG + g)) * CP + c];
#pragma unroll
    for (int g = 0; g < NG; ++g) {
        if (g < NG - 1) {
            const float ta = target[((size_t)b * TT + g * GLEN) * 4];
            const float te = target[((size_t)b * TT + (g + 1) * GLEN) * 4];
            GP[g] = __expf(-(te - ta) * INV_TEMP);
        } else GP[g] = 0.f;
    }
    float carry = 0.f;
#pragma unroll
    for (int g = NG - 1; g >= 0; --g) {
        SC[((size_t)(b * NG + g)) * CP + c] = carry;
        carry = fmaf(GP[g], carry, Gv[g]);
    }
}

// ------- Phase 3: replay + fused loss, POLARITY-PLANE SPLIT; DPP-hybrid reduction -------
__global__ __launch_bounds__(256, 8) void p3_loss(const float* __restrict__ pred,
                                                  const float* __restrict__ target,
                                                  const float* __restrict__ LCin,
                                                  const float* __restrict__ SC,
                                                  double* __restrict__ partials) {
    const int blk = blockIdx.x;            // BB*KCH/4
    const int q = blockIdx.y;              // plane/polarity this wave serves
    const int b = blk >> 6;
    const int k0 = (blk & 63) << 2;
    const int tid = threadIdx.x;
    const int w = tid >> 6, lane = tid & 63;
    const int k = k0 + w;
    const int g = k >> 4;
    const int a = k * LCH;

    __shared__ float4 tg4[4][LCH];         // one ds_read_b128 per step
    __shared__ float tnextS[4];
    if (tid < 64) {
        const float4* __restrict__ tgl =
            (const float4*)(target + ((size_t)b * TT + k0 * LCH) * 4);
        ((float4*)tg4)[tid] = tgl[tid];
    }
    if (tid < 4) {
        const int kk = k0 + tid;
        tnextS[tid] = (kk < KCH - 1) ? target[((size_t)b * TT + (kk + 1) * LCH) * 4] : 0.0f;
    }
    __syncthreads();

    // carry(k) = LCin[k] + Qk * SC[group] (plane-q slice only)
    float Qk = 0.f;
    if (g < NG - 1) {
        const float tge = target[((size_t)b * TT + (g + 1) * GLEN) * 4];
        const float tk1 = target[((size_t)b * TT + (k + 1) * LCH) * 4];
        Qk = __expf(-(tge - tk1) * INV_TEMP);
    }

    const float* __restrict__ lc = LCin + (size_t)(b * KCH + k) * CP + q * HALF;
    const float* __restrict__ sc = SC + ((size_t)(b * NG + g)) * CP + q * HALF;
    float s[NJ];
#pragma unroll
    for (int j = 0; j < NJ; ++j) {
        const int u = lane + 64 * j;
        s[j] = fmaf(Qk, sc[u], lc[u]);
    }

    double lacc = 0.0;
    float tnext_run = tnextS[w];           // t_{i+1}, carried across iterations
    for (int li = LCH - 1; li >= 0; --li) {
        const int i = a + li;
        const float4 tv = tg4[w][li];
        const float ti = tv.x;
        const float tn = tnext_run;
        tnext_run = ti;
        const float d = (i == 0 || i >= TT - 1) ? 0.0f : __expf(-(tn - ti) * INV_TEMP);
        const int y = (int)tv.y, x = (int)tv.z, p = (int)tv.w;

        if (p != q) {                       // inactive step: pure decay (wave-uniform)
#pragma unroll
            for (int j = 0; j < NJ; ++j) s[j] *= d;
            continue;
        }

        const int uy = y, ux = 260 + x;
        const float* __restrict__ prow = pred + ((size_t)b * TT + i) * CC;

        float zpy = 0.f, zsy = 0.f, dty = 0.f;
        float zpx = 0.f, zsx = 0.f, dtx = 0.f;
#pragma unroll
        for (int j = 0; j < NJ; ++j) {
            const int u = lane + 64 * j;
            const float add = (u == uy ? 1.f : 0.f) + (u == ux ? 1.f : 0.f);
            s[j] = fmaf(s[j], d, add);
            const int c = (u < 260) ? q * HH + u : 2 * HH + q * WW + (u - 260);
            const float pr = (u < NA) ? prow[c] : 0.0f;
            float es = __expf(s[j]);
            float ep = __expf(pr);
            if (j == NJ - 1) {               // mask pad lanes (u >= 606)
                const float m = (u < NA) ? 1.f : 0.f;
                es *= m; ep *= m;
            }
            if (j < 4) {                     // u <= 255: pure y
                zpy += ep; zsy += es; dty = fmaf(es, pr, dty);
            } else if (j == 4) {             // u in [256,320): mixed at 260
                const bool isY = (u < 260);
                zpy += isY ? ep : 0.f;
                zsy += isY ? es : 0.f;
                dty = fmaf(isY ? es : 0.f, pr, dty);
                zpx += isY ? 0.f : ep;
                zsx += isY ? 0.f : es;
                dtx = fmaf(isY ? 0.f : es, pr, dtx);
            } else {                         // pure x
                zpx += ep; zsx += es; dtx = fmaf(es, pr, dtx);
            }
        }

        zpy = wave_sum(zpy); zsy = wave_sum(zsy); dty = wave_sum(dty);
        zpx = wave_sum(zpx); zsx = wave_sum(zsx); dtx = wave_sum(dtx);

        const float loss = __logf(zpy) + __logf(zpx)
                         - __fdividef(dty, zsy) - __fdividef(dtx, zsx);
        lacc += (double)loss;
    }
    if (lane == 0) partials[q * (BB * KCH) + b * KCH + k] = lacc;
}

// ---------------- Finalize: sum 2*B*KCH partials ----------------
__global__ void p4_final(const double* __restrict__ partials, float* __restrict__ out) {
    const int tid = threadIdx.x;   // 256
    double sum = 0.0;
    for (int i = tid; i < 2 * BB * KCH; i += 256) sum += partials[i];
#pragma unroll
    for (int off = 32; off > 0; off >>= 1) sum += __shfl_xor(sum, off);
    __shared__ double sred[4];
    if ((tid & 63) == 0) sred[tid >> 6] = sum;
    __syncthreads();
    if (tid == 0)
        out[0] = (float)((sred[0] + sred[1] + sred[2] + sred[3]) / (double)((size_t)BB * TT));
}

extern "C" void kernel_launch(void* const* d_in, const int* in_sizes, int n_in,
                              void* d_out, int out_size, void* d_ws, size_t ws_size,
                              hipStream_t stream) {
    const float* pred   = (const float*)d_in[0];
    const float* target = (const float*)d_in[1];
    float* out = (float*)d_out;

    // ws layout: [partials 8192 doubles = 64KB][Lbuf][LCin][GroupL][SC]
    double* partials = (double*)d_ws;
    float* Lbuf   = (float*)((char*)d_ws + 65536);
    float* LCin   = Lbuf + (size_t)BB * KCH * CP;
    float* GroupL = LCin + (size_t)BB * KCH * CP;
    float* SC     = GroupL + (size_t)BB * NG * CP;

    p1_local<<<BB * KCH / 4, 256, 0, stream>>>(target, Lbuf);
    p2a<<<BB * NG * 5, 256, 0, stream>>>(target, Lbuf, LCin, GroupL);
    p2b<<<BB * 5, 256, 0, stream>>>(target, GroupL, SC);
    dim3 g3(BB * KCH / 4, 2);
    p3_loss<<<g3, 256, 0, stream>>>(pred, target, LCin, SC, partials);
    p4_final<<<1, 256, 0, stream>>>(partials, out);
}